// Round 6
// baseline (349.397 us; speedup 1.0000x reference)
//
#include <hip/hip_runtime.h>
#include <hip/hip_bf16.h>
#include <cstdint>

#define B_   2
#define N_   1024
#define DN_  128
#define DE_  16
#define DG_  128
#define MID_ 64
#define OUT_ 128
#define TI_  2
#define PR_ROWS 4

typedef short bf16x8 __attribute__((ext_vector_type(8)));
typedef float f32x4  __attribute__((ext_vector_type(4)));

__device__ inline short f2bf(float f) {
    union { float f; unsigned u; } v; v.f = f;
    unsigned r = v.u + 0x7FFFu + ((v.u >> 16) & 1u);   // RTNE
    return (short)(unsigned short)(r >> 16);
}

__device__ inline unsigned pk2(float lo, float hi) {
    union { __hip_bfloat162 h; unsigned u; } p;
    p.h = __float22bfloat162_rn(make_float2(lo, hi));  // v_cvt_pk_bf16_f32
    return p.u;
}

// ---------------------------------------------------------------------------
// Fused prep kernel (unchanged from R5 — not the bottleneck).
// ---------------------------------------------------------------------------
__global__ void __launch_bounds__(384) prep_all(
    const float* __restrict__ features, const float* __restrict__ g_features,
    const float* __restrict__ Wm, const float* __restrict__ bm,
    const float* __restrict__ Wskip, const float* __restrict__ bskip,
    const float* __restrict__ W1, const float* __restrict__ b1,
    const float* __restrict__ W2, const float* __restrict__ b2,
    const float* __restrict__ We, const float* __restrict__ be,
    const float* __restrict__ Wg, const float* __restrict__ bg,
    float* __restrict__ values, float* __restrict__ skipo,
    float* __restrict__ P1x, float* __restrict__ p2,
    float* __restrict__ pg, short* __restrict__ We_frag)
{
    const int t   = threadIdx.x;
    const int blk = blockIdx.x;

    if (blk == 512) {                       // --- We fragment prep ---
        for (int e = t; e < 4 * 64 * 8; e += 384) {
            const int c    = e >> 9;
            const int lane = (e >> 3) & 63;
            const int j    = e & 7;
            const int quad = lane >> 4, s = lane & 15;
            short v = 0;
            if (quad < 2) v = f2bf(We[(quad * 8 + j) * MID_ + c * 16 + s]);
            We_frag[e] = v;
        }
        return;
    }
    if (blk == 513) {                       // --- pg ---
        if (t < MID_) {
            float a0 = bg[t], a1 = bg[t];
            for (int k = 0; k < DG_; ++k) {
                const float w = Wg[k * MID_ + t];
                a0 += g_features[k] * w;
                a1 += g_features[DG_ + k] * w;
            }
            pg[t] = a0; pg[MID_ + t] = a1;
        }
        return;
    }

    // --- per-node projections ---
    const int r0 = blk * PR_ROWS;
    __shared__ float feat[PR_ROWS][DN_];
    for (int idx = t; idx < PR_ROWS * DN_; idx += 384)
        feat[idx >> 7][idx & 127] = features[(size_t)r0 * DN_ + idx];
    __syncthreads();

    const float* W; int c, stride; float base; float* outp; int ostride;
    if (t < 128) {
        W = Wm;    c = t;       stride = OUT_; base = bm[c];
        outp = values + (size_t)r0 * OUT_ + c; ostride = OUT_;
    } else if (t < 256) {
        W = Wskip; c = t - 128; stride = OUT_; base = bskip[c];
        outp = skipo + (size_t)r0 * OUT_ + c;  ostride = OUT_;
    } else if (t < 320) {
        W = W1;    c = t - 256; stride = MID_; base = b1[c] + be[c];
        outp = P1x + (size_t)r0 * MID_ + c;    ostride = MID_;
    } else {
        W = W2;    c = t - 320; stride = MID_; base = b2[c];
        outp = p2 + (size_t)r0 * MID_ + c;     ostride = MID_;
    }

    float acc[PR_ROWS] = {};
    for (int k = 0; k < DN_; ++k) {
        const float w = W[k * stride + c];
        #pragma unroll
        for (int q = 0; q < PR_ROWS; ++q) acc[q] += feat[q][k] * w;
    }
    #pragma unroll
    for (int q = 0; q < PR_ROWS; ++q) outp[q * ostride] = acc[q] + base;
}

// ---------------------------------------------------------------------------
// Main fused kernel: 1024 blocks x 256 threads (4 waves), TI=2 i-rows/block.
// 16 waves/CU demand (~4 blocks/CU) vs R5's 8 — restores latency hiding
// while keeping P1x/values reuse across the 2 i-rows.
// ---------------------------------------------------------------------------
__global__ void __launch_bounds__(256) gat_main(
    const float* __restrict__ e_features, const float* __restrict__ adj,
    const short* __restrict__ We_frag, const float* __restrict__ Wa,
    const float* __restrict__ values, const float* __restrict__ skipo,
    const float* __restrict__ P1x, const float* __restrict__ p2,
    const float* __restrict__ pg, float* __restrict__ out)
{
    const int t    = threadIdx.x;
    const int wv   = t >> 6;
    const int l    = t & 63;
    const int quad = l >> 4;
    const int s    = l & 15;
    const int r    = blockIdx.x;
    const int b    = (r >> 2) & 1;                    // XCD -> one batch
    const int i0   = ((((r >> 3) << 2) | (r & 3))) * TI_;

    __shared__ float lgP[TI_][N_];                    // 8 KB
    __shared__ float4 redc[TI_][4][32];               // 4 KB
    __shared__ float smax[4], ssum[4];

    // ---- block constants ----
    bf16x8 bfr[4];
    float  wa_r[4], p2i[TI_][4];
    #pragma unroll
    for (int c = 0; c < 4; ++c) {
        bfr[c]  = *(const bf16x8*)&We_frag[(c * 64 + l) * 8];
        wa_r[c] = Wa[c * 16 + s];
        const float pgc = pg[b * MID_ + c * 16 + s];
        #pragma unroll
        for (int ii = 0; ii < TI_; ++ii)
            p2i[ii][c] = p2[((size_t)(b * N_ + i0 + ii)) * MID_ + c * 16 + s] + pgc;
    }
    const size_t erow0 = (size_t)(b * N_ + i0) * N_;

    // ---- Pass A: software-pipelined MFMA logits ----
    float4 eA[TI_][2];
    if (quad < 2) {
        #pragma unroll
        for (int ii = 0; ii < TI_; ++ii) {
            const float* ep = &e_features[(erow0 + (size_t)ii * N_ + wv * 16 + s) * DE_ + quad * 8];
            eA[ii][0] = *(const float4*)ep;
            eA[ii][1] = *(const float4*)(ep + 4);
        }
    }
    for (int it = 0; it < 16; ++it) {
        const int tile = wv + it * 4;
        const int j0   = tile * 16;

        // pack current tile
        unsigned af[TI_][4];
        #pragma unroll
        for (int ii = 0; ii < TI_; ++ii) {
            if (quad < 2) {
                af[ii][0] = pk2(eA[ii][0].x, eA[ii][0].y);
                af[ii][1] = pk2(eA[ii][0].z, eA[ii][0].w);
                af[ii][2] = pk2(eA[ii][1].x, eA[ii][1].y);
                af[ii][3] = pk2(eA[ii][1].z, eA[ii][1].w);
            } else {
                af[ii][0] = af[ii][1] = af[ii][2] = af[ii][3] = 0u;
            }
        }
        // prefetch next tile
        if (it < 15) {
            const int jn = (tile + 4) * 16;
            if (quad < 2) {
                #pragma unroll
                for (int ii = 0; ii < TI_; ++ii) {
                    const float* ep = &e_features[(erow0 + (size_t)ii * N_ + jn + s) * DE_ + quad * 8];
                    eA[ii][0] = *(const float4*)ep;
                    eA[ii][1] = *(const float4*)(ep + 4);
                }
            }
        }
        // P1x tile (shared by both i-rows)
        float base[4][4];
        {
            const float* pb = &P1x[((size_t)(b * N_) + j0 + quad * 4) * MID_ + s];
            #pragma unroll
            for (int c = 0; c < 4; ++c)
                #pragma unroll
                for (int rr = 0; rr < 4; ++rr)
                    base[c][rr] = pb[rr * MID_ + c * 16];
        }
        #pragma unroll
        for (int ii = 0; ii < TI_; ++ii) {
            union { unsigned u[4]; bf16x8 v; } a;
            a.u[0] = af[ii][0]; a.u[1] = af[ii][1];
            a.u[2] = af[ii][2]; a.u[3] = af[ii][3];
            f32x4 acc[4];
            #pragma unroll
            for (int c = 0; c < 4; ++c) {
                #pragma unroll
                for (int rr = 0; rr < 4; ++rr)
                    acc[c][rr] = base[c][rr] + p2i[ii][c];
                acc[c] = __builtin_amdgcn_mfma_f32_16x16x32_bf16(a.v, bfr[c], acc[c], 0, 0, 0);
            }
            float tt[4];
            #pragma unroll
            for (int rr = 0; rr < 4; ++rr) {
                float x0 = acc[0][rr]; x0 = fmaxf(x0, 0.01f * x0);
                float x1 = acc[1][rr]; x1 = fmaxf(x1, 0.01f * x1);
                float x2 = acc[2][rr]; x2 = fmaxf(x2, 0.01f * x2);
                float x3 = acc[3][rr]; x3 = fmaxf(x3, 0.01f * x3);
                tt[rr] = x0 * wa_r[0] + x1 * wa_r[1] + x2 * wa_r[2] + x3 * wa_r[3];
            }
            #pragma unroll
            for (int o = 1; o < 16; o <<= 1) {
                tt[0] += __shfl_xor(tt[0], o);
                tt[1] += __shfl_xor(tt[1], o);
                tt[2] += __shfl_xor(tt[2], o);
                tt[3] += __shfl_xor(tt[3], o);
            }
            if (s < 4) lgP[ii][j0 + quad * 4 + s] = tt[s];
        }
    }
    __syncthreads();

    // ---- Pass B: masked softmax, threads 0-127 plane 0, 128-255 plane 1 ----
    {
        const int tt8 = (t & 127) * 8;
        const int p   = t >> 7;
        const size_t arb = (size_t)(b * N_ + i0 + p) * N_;
        float4 lv0 = *(const float4*)&lgP[p][tt8];
        float4 lv1 = *(const float4*)&lgP[p][tt8 + 4];
        float4 av0 = *(const float4*)&adj[arb + tt8];
        float4 av1 = *(const float4*)&adj[arb + tt8 + 4];
        const float NEG = -3.4e38f;
        float m = NEG;
        m = fmaxf(m, av0.x > 0.f ? lv0.x : NEG);
        m = fmaxf(m, av0.y > 0.f ? lv0.y : NEG);
        m = fmaxf(m, av0.z > 0.f ? lv0.z : NEG);
        m = fmaxf(m, av0.w > 0.f ? lv0.w : NEG);
        m = fmaxf(m, av1.x > 0.f ? lv1.x : NEG);
        m = fmaxf(m, av1.y > 0.f ? lv1.y : NEG);
        m = fmaxf(m, av1.z > 0.f ? lv1.z : NEG);
        m = fmaxf(m, av1.w > 0.f ? lv1.w : NEG);
        #pragma unroll
        for (int o = 1; o < 64; o <<= 1) m = fmaxf(m, __shfl_xor(m, o));
        if (l == 0) smax[wv] = m;
        __syncthreads();
        m = fmaxf(smax[p * 2], smax[p * 2 + 1]);
        float4 e0, e1;
        e0.x = av0.x > 0.f ? __expf(lv0.x - m) : 0.f;
        e0.y = av0.y > 0.f ? __expf(lv0.y - m) : 0.f;
        e0.z = av0.z > 0.f ? __expf(lv0.z - m) : 0.f;
        e0.w = av0.w > 0.f ? __expf(lv0.w - m) : 0.f;
        e1.x = av1.x > 0.f ? __expf(lv1.x - m) : 0.f;
        e1.y = av1.y > 0.f ? __expf(lv1.y - m) : 0.f;
        e1.z = av1.z > 0.f ? __expf(lv1.z - m) : 0.f;
        e1.w = av1.w > 0.f ? __expf(lv1.w - m) : 0.f;
        *(float4*)&lgP[p][tt8]     = e0;
        *(float4*)&lgP[p][tt8 + 4] = e1;
        float sum = ((e0.x + e0.y) + (e0.z + e0.w)) + ((e1.x + e1.y) + (e1.z + e1.w));
        #pragma unroll
        for (int o = 1; o < 64; o <<= 1) sum += __shfl_xor(sum, o);
        if (l == 0) ssum[wv] = sum;
        __syncthreads();
    }

    // ---- Pass C: (exp @ values) shared across the 2 i-rows ----
    {
        const int cg = t & 31;          // float4 channel group
        const int jp = t >> 5;          // j partition 0..7
        const float* vb = values + (size_t)b * N_ * OUT_ + cg * 4;
        float4 a0 = make_float4(0.f, 0.f, 0.f, 0.f);
        float4 a1 = make_float4(0.f, 0.f, 0.f, 0.f);
        for (int j = jp; j < N_; j += 8) {
            const float w0 = lgP[0][j];
            const float w1 = lgP[1][j];
            const float4 v = *(const float4*)&vb[(size_t)j * OUT_];
            a0.x += w0 * v.x; a0.y += w0 * v.y; a0.z += w0 * v.z; a0.w += w0 * v.w;
            a1.x += w1 * v.x; a1.y += w1 * v.y; a1.z += w1 * v.z; a1.w += w1 * v.w;
        }
        a0.x += __shfl_xor(a0.x, 32); a0.y += __shfl_xor(a0.y, 32);
        a0.z += __shfl_xor(a0.z, 32); a0.w += __shfl_xor(a0.w, 32);
        a1.x += __shfl_xor(a1.x, 32); a1.y += __shfl_xor(a1.y, 32);
        a1.z += __shfl_xor(a1.z, 32); a1.w += __shfl_xor(a1.w, 32);
        if (l < 32) {
            redc[0][wv][l] = a0;
            redc[1][wv][l] = a1;
        }
    }
    __syncthreads();
    if (t < 64) {
        const int ch4 = t & 31, p = t >> 5;
        const float4 r0 = redc[p][0][ch4], r1 = redc[p][1][ch4];
        const float4 r2 = redc[p][2][ch4], r3 = redc[p][3][ch4];
        const float inv = 1.0f / (ssum[p * 2] + ssum[p * 2 + 1]);
        const size_t ob = ((size_t)(b * N_ + i0 + p)) * OUT_ + ch4 * 4;
        const float4 sk = *(const float4*)&skipo[ob];
        float4 o;
        o.x = fmaxf((r0.x + r1.x + r2.x + r3.x) * inv + sk.x, 0.f);
        o.y = fmaxf((r0.y + r1.y + r2.y + r3.y) * inv + sk.y, 0.f);
        o.z = fmaxf((r0.z + r1.z + r2.z + r3.z) * inv + sk.z, 0.f);
        o.w = fmaxf((r0.w + r1.w + r2.w + r3.w) * inv + sk.w, 0.f);
        *(float4*)&out[ob] = o;
    }
}

extern "C" void kernel_launch(void* const* d_in, const int* in_sizes, int n_in,
                              void* d_out, int out_size, void* d_ws, size_t ws_size,
                              hipStream_t stream) {
    const float* features   = (const float*)d_in[0];
    const float* e_features = (const float*)d_in[1];
    const float* g_features = (const float*)d_in[2];
    const float* adj        = (const float*)d_in[3];
    const float* Wm    = (const float*)d_in[4];
    const float* bm    = (const float*)d_in[5];
    const float* Wskip = (const float*)d_in[6];
    const float* bskip = (const float*)d_in[7];
    const float* W1    = (const float*)d_in[8];
    const float* b1    = (const float*)d_in[9];
    const float* W2    = (const float*)d_in[10];
    const float* b2    = (const float*)d_in[11];
    const float* We    = (const float*)d_in[12];
    const float* be    = (const float*)d_in[13];
    const float* Wg    = (const float*)d_in[14];
    const float* bg    = (const float*)d_in[15];
    const float* Wa    = (const float*)d_in[16];
    float* out = (float*)d_out;

    float* ws      = (float*)d_ws;
    float* values  = ws;                    // 262144
    float* skipo   = ws + 262144;           // 262144
    float* P1x     = ws + 524288;           // 131072
    float* p2      = ws + 655360;           // 131072
    float* pg      = ws + 786432;           // 128
    short* We_frag = (short*)(ws + 786560); // 2048 shorts

    prep_all<<<B_ * N_ / PR_ROWS + 2, 384, 0, stream>>>(
        features, g_features, Wm, bm, Wskip, bskip, W1, b1, W2, b2,
        We, be, Wg, bg, values, skipo, P1x, p2, pg, We_frag);
    gat_main<<<B_ * N_ / TI_, 256, 0, stream>>>(
        e_features, adj, We_frag, Wa, values, skipo, P1x, p2, pg, out);
}